// Round 8
// baseline (136.257 us; speedup 1.0000x reference)
//
#include <hip/hip_runtime.h>

// SupConLoss, B=8192, D=128, T=5.0
// v9: barrier-free register main (v2's proven pipeline) x triangle symmetry
//     x max-free math; riders in prep (separate regalloc — v8's 136-VGPR cliff fix).
//   - main: no LDS, no __syncthreads. Each wave independent: 32 rows in regs,
//     B fragments ping-pong prefetched from L2 (Fb=2MB, fully L2-resident).
//   - triangle 128x256 tiles (1056 blocks): (2k,k)+(2k+1,k) = full diag block
//     (row-credit only, diag zeroed); below-tiles dual-credit row+col.
//   - part slots: row slot cy (plain store, single writer); col slot 32+(bx>>1)
//     (atomicAdd). Row i reads slots [0..c2] u [32+c2+1..63], exactly 32.
//   - math: e = 2^(raw*invT*log2e - 40); m~ = ||f||^2/T exact (m only enters
//     via the 1e-12 term); term = (A-cnt*m~)/cnt - log(1e-12 + Z*e^{C40-m~}).

#define BN 8192
#define DK 128
#define INV_T 0.2f
#define C1F 0.28853901f     // INV_T * log2(e)
#define C40F 27.7258872f    // 40 * ln(2)

#define TILES 1056          // sum_{bx=0}^{63} (bx/2 + 1), 128x256 tiles
#define PSLOTS 64

#define NCLS 100
#define PB 128              // prep streaming blocks
#define PROWS (BN / PB)     // 64

#define FBLKS 128           // finalize blocks (64 threads each)

// workspace layout (bytes)
#define OFF_FB    0                                 // 2 MB bf16 features
#define OFF_PART  (2 * 1024 * 1024)                 // 2 MB float [PSLOTS][BN]
#define OFF_G     (OFF_PART + PSLOTS * BN * 4)      // 51.2 KB class sums
#define OFF_HIST  (OFF_G + NCLS * DK * 4)           // hist
#define OFF_BSUM  (OFF_HIST + 512)                  // block sums (FBLKS floats)
#define OFF_CTR   (OFF_BSUM + 1024)                 // arrival counter

typedef __attribute__((ext_vector_type(8))) short bf16x8;   // 8 bf16 = 4 VGPRs
typedef __attribute__((ext_vector_type(4))) float f32x4;

__device__ __forceinline__ unsigned short f2bf(float f) {
    unsigned u = __builtin_bit_cast(unsigned, f);
    u += 0x7fffu + ((u >> 16) & 1u);
    return (unsigned short)(u >> 16);
}

__device__ __forceinline__ float fexp2(float x) {
#if __has_builtin(__builtin_amdgcn_exp2f)
    return __builtin_amdgcn_exp2f(x);
#else
    float r; asm("v_exp_f32 %0, %1" : "=v"(r) : "v"(x)); return r;
#endif
}

// rider block: class c — compact matching rows, sum F rows -> G[c], hist[c]
__device__ __forceinline__ void class_rider(const float* __restrict__ F,
                                            const int* __restrict__ labels,
                                            float* __restrict__ G,
                                            int* __restrict__ hist, int c) {
    const int t = threadIdx.x;
    __shared__ int   rows[2048];
    __shared__ int   nrs;
    __shared__ float gh[256];

    if (t == 0) nrs = 0;
    __syncthreads();
#pragma unroll
    for (int k = 0; k < BN / 256; ++k) {   // 32
        const int r = k * 256 + t;
        if (labels[r] == c) {
            const int idx = atomicAdd(&nrs, 1);
            if (idx < 2048) rows[idx] = r;
        }
    }
    __syncthreads();
    const int n = nrs;

    // 256 threads = 2 halves x 128 cols; each sums its half's rows serially
    const int half = t >> 7, col = t & 127;
    float acc = 0.f;
    for (int j = half; j < n; j += 2)
        acc += F[(size_t)rows[j] * DK + col];
    gh[t] = acc;
    __syncthreads();
    if (t < DK) G[c * DK + t] = gh[t] + gh[t + DK];
    if (t == 0) hist[c] = n;
}

// prep: blocks [0,PB) stream (cast + zero col-slots + ctr); [PB,PB+NCLS) riders
__global__ __launch_bounds__(256) void prep_kernel(const float* __restrict__ F,
                                                   const int* __restrict__ labels,
                                                   unsigned short* __restrict__ Fb,
                                                   float* __restrict__ part,
                                                   float* __restrict__ G,
                                                   int* __restrict__ hist,
                                                   unsigned int* __restrict__ ctr) {
    const int t = threadIdx.x;
    const int b = blockIdx.x;

    if (b >= PB) { class_rider(F, labels, G, hist, b - PB); return; }

    if (b == 0 && t == 0) *ctr = 0u;   // re-arm finalize's last-block counter

    // zero col-side slots: 1 MB / 128 blocks = 512 float4 per block
    {
        float4* pz = (float4*)(part + (size_t)32 * BN) + (size_t)b * 512;
        pz[t]       = make_float4(0.f, 0.f, 0.f, 0.f);
        pz[t + 256] = make_float4(0.f, 0.f, 0.f, 0.f);
    }

    // cast: 64 rows = 2048 float4 per block
    const float4* F4  = (const float4*)F + (size_t)b * (PROWS * DK / 4);
    ushort4*      Fb4 = (ushort4*)Fb + (size_t)b * (PROWS * DK / 4);
#pragma unroll
    for (int k = 0; k < PROWS * DK / 4 / 256; ++k) {   // 8
        float4 v = F4[k * 256 + t];
        ushort4 o;
        o.x = f2bf(v.x); o.y = f2bf(v.y); o.z = f2bf(v.z); o.w = f2bf(v.w);
        Fb4[k * 256 + t] = o;
    }
}

// one 128-row x 256-col tile at (bx, cy), cy <= bx>>1. No LDS, no barriers.
template <bool DIAGT>
__device__ __forceinline__ void supcon_tile(const short* __restrict__ Fb,
                                            float* __restrict__ part,
                                            int bx, int cy) {
    const int t    = threadIdx.x;
    const int wave = t >> 6, lane = t & 63;
    const int quad = lane >> 4, l16 = lane & 15;
    const int rowBase = bx * 128 + wave * 32;
    const int colBase = cy * 256;

    // A fragments: 32 rows x K=128 per wave, resident for the whole tile
    bf16x8 a[2][4];
#pragma unroll
    for (int rt = 0; rt < 2; ++rt)
#pragma unroll
        for (int kt = 0; kt < 4; ++kt)
            a[rt][kt] = *(const bf16x8*)(Fb + (size_t)(rowBase + rt * 16 + l16) * DK
                                            + kt * 32 + quad * 8);

    float Zs[2][4];
#pragma unroll
    for (int rt = 0; rt < 2; ++rt)
#pragma unroll
        for (int r = 0; r < 4; ++r) Zs[rt][r] = 0.f;

    float* const colpart = part + (size_t)(32 + (bx >> 1)) * BN + colBase;

    // B fragment pointer for this lane: column (colBase + jt*16 + l16)
    const short* bp = Fb + (size_t)(colBase + l16) * DK + quad * 8;
    bf16x8 bc[4], bn[4];
#pragma unroll
    for (int kt = 0; kt < 4; ++kt) bc[kt] = *(const bf16x8*)(bp + kt * 32);

    auto STEP = [&](const bf16x8 (&bb)[4], int jt) {
        float Zc = 0.f;
#pragma unroll
        for (int rt = 0; rt < 2; ++rt) {
            f32x4 acc = {0.f, 0.f, 0.f, 0.f};
#pragma unroll
            for (int kt = 0; kt < 4; ++kt)
                acc = __builtin_amdgcn_mfma_f32_16x16x32_bf16(a[rt][kt], bb[kt],
                                                              acc, 0, 0, 0);
#pragma unroll
            for (int r = 0; r < 4; ++r) {
                float e = fexp2(fmaf(acc[r], C1F, -40.0f));
                if (DIAGT) {
                    if (colBase + jt * 16 + l16 == rowBase + rt * 16 + quad * 4 + r)
                        e = 0.f;                       // Z excludes diagonal
                }
                Zs[rt][r] += e;                        // row-side
                if (!DIAGT) Zc += e;                   // col-side
            }
        }
        if (!DIAGT) {   // reduce over the 4 quads (this wave's 32 rows)
            Zc += __shfl_xor(Zc, 16);
            Zc += __shfl_xor(Zc, 32);
            if (quad == 0) atomicAdd(colpart + jt * 16 + l16, Zc);   // fire & forget
        }
    };

    for (int jt = 0; jt < 16; jt += 2) {
        bp += 16 * DK;
#pragma unroll
        for (int kt = 0; kt < 4; ++kt) bn[kt] = *(const bf16x8*)(bp + kt * 32);
        STEP(bc, jt);
        if (jt + 2 < 16) {
            bp += 16 * DK;
#pragma unroll
            for (int kt = 0; kt < 4; ++kt) bc[kt] = *(const bf16x8*)(bp + kt * 32);
        }
        STEP(bn, jt + 1);
    }

    // row-side: slot cy single-writer across the grid -> plain store
#pragma unroll
    for (int rt = 0; rt < 2; ++rt)
#pragma unroll
        for (int r = 0; r < 4; ++r) {
            float zz = Zs[rt][r];
#pragma unroll
            for (int h = 1; h < 16; h <<= 1) zz += __shfl_xor(zz, h);
            if (l16 == 0)
                part[(size_t)cy * BN + rowBase + rt * 16 + quad * 4 + r] = zz;
        }
}

__global__ __launch_bounds__(256) void supcon_main(const short* __restrict__ Fb,
                                                   float* __restrict__ part) {
    const int bid = blockIdx.x;
    // decode: ranges [k^2, k^2+k) -> bx=2k-1; [k^2+k, (k+1)^2) -> bx=2k
    int k0 = (int)sqrtf((float)bid);
    while ((k0 + 1) * (k0 + 1) <= bid) ++k0;
    while (k0 * k0 > bid) --k0;
    int bx, cy;
    if (bid < k0 * k0 + k0) { bx = 2 * k0 - 1; cy = bid - k0 * k0; }
    else                    { bx = 2 * k0;     cy = bid - k0 * k0 - k0; }
    if (cy == (bx >> 1)) supcon_tile<true >(Fb, part, bx, cy);
    else                 supcon_tile<false>(Fb, part, bx, cy);
}

// 128 blocks x 64 threads: 64 rows per block (row-chunk c2 = bid>>2 uniform)
__global__ __launch_bounds__(64) void supcon_finalize(const float* __restrict__ F,
                                                      const int* __restrict__ labels,
                                                      const float* __restrict__ part,
                                                      const float* __restrict__ G,
                                                      const int* __restrict__ hist,
                                                      float* __restrict__ bsums,
                                                      unsigned int* __restrict__ ctr,
                                                      float* __restrict__ out) {
    const int t  = threadIdx.x;
    const int i  = blockIdx.x * 64 + t;
    const int c2 = blockIdx.x >> 2;   // i / 256, block-uniform

    // row i's Z: row-side slots [0..c2], col-side slots [32+c2+1..63] = 32 reads
    float Zm = 0.f;
#pragma unroll 8
    for (int k = 0; k < 32; ++k) {
        const int slot = (k <= c2) ? k : 32 + k;
        Zm += part[(size_t)slot * BN + i];
    }

    const int   lbl = labels[i];
    const float cnt = (float)(hist[lbl] - 1);

    const float4* fr = (const float4*)(F + (size_t)i * DK);
    const float4* gr = (const float4*)(G + lbl * DK);
    float dot = 0.f, nrm = 0.f;
#pragma unroll 8
    for (int k = 0; k < DK / 4; ++k) {
        const float4 av = fr[k], gv = gr[k];
        dot += av.x * gv.x + av.y * gv.y + av.z * gv.z + av.w * gv.w;
        nrm += av.x * av.x + av.y * av.y + av.z * av.z + av.w * av.w;
    }

    // m~ = s_ii/T; exact for any m~ (m only enters via the 1e-12 term)
    const float mt = nrm * INV_T;
    const float A  = (dot - nrm) * INV_T;
    float term = 0.f;
    if (cnt > 0.5f)
        term = (A - cnt * mt) / cnt - __logf(1e-12f + Zm * __expf(C40F - mt));

    float sum = term;
#pragma unroll
    for (int h = 1; h < 64; h <<= 1) sum += __shfl_xor(sum, h);

    __shared__ int lastf;
    if (t == 0) {
        bsums[blockIdx.x] = sum;
        __threadfence();
        const unsigned old = atomicAdd(ctr, 1u);
        lastf = (old == FBLKS - 1);
    }
    __syncthreads();
    if (lastf) {   // last block: wave-parallel fold of FBLKS partials
        const volatile float* vb = bsums;
        float v = vb[t] + vb[t + 64];
#pragma unroll
        for (int h = 1; h < 64; h <<= 1) v += __shfl_xor(v, h);
        if (t == 0) out[0] = -v * (1.0f / BN);
    }
}

extern "C" void kernel_launch(void* const* d_in, const int* in_sizes, int n_in,
                              void* d_out, int out_size, void* d_ws, size_t ws_size,
                              hipStream_t stream) {
    const float* F      = (const float*)d_in[0];
    const int*   labels = (const int*)d_in[1];
    // d_in[2] (fac_label) is a no-op in the reference math.
    float* out = (float*)d_out;
    char*  ws  = (char*)d_ws;

    unsigned short* Fb    = (unsigned short*)(ws + OFF_FB);
    float*          part  = (float*)(ws + OFF_PART);
    float*          G     = (float*)(ws + OFF_G);
    int*            hist  = (int*)(ws + OFF_HIST);
    float*          bsums = (float*)(ws + OFF_BSUM);
    unsigned int*   ctr   = (unsigned int*)(ws + OFF_CTR);

    prep_kernel<<<PB + NCLS, 256, 0, stream>>>(F, labels, Fb, part, G, hist, ctr);
    supcon_main<<<TILES, 256, 0, stream>>>((const short*)Fb, part);
    supcon_finalize<<<FBLKS, 64, 0, stream>>>(F, labels, part, G, hist,
                                              bsums, ctr, out);
}

// Round 9
// 117.626 us; speedup vs baseline: 1.1584x; 1.1584x over previous
//
#include <hip/hip_runtime.h>

// SupConLoss, B=8192, D=128, T=5.0
// v10: best-of-all-rounds recombination.
//   - main tiles = v7's LDS-staged 128x256 triangle tiles (best measured main)
//     with col-side ATOMICS REPLACED by per-tile records (LDS reduce -> plain
//     store, single writer, no zeroing): crec[bid][256].
//   - riders (per-class G/hist) ride in main's grid (v8 chain) but kernel is
//     __launch_bounds__(256,2)-capped so they can't push VGPR past the 128
//     cliff (v8's regression).
//   - prep: pure cast + ctr. finalize: 128x64, Zm = row-slots + crec walk.
// Math (verified v5+): e = 2^(raw*invT*log2e - 40); m~ = ||f||^2/T exact;
// term = (A - cnt*m~)/cnt - log(1e-12 + Z*e^{C40-m~}); loss = -(1/B) sum term.

#define BN 8192
#define DK 128
#define INV_T 0.2f
#define C1F 0.28853901f     // INV_T * log2(e)
#define C40F 27.7258872f    // 40 * ln(2)

#define TILES 1056          // sum_{bx=0}^{63} (bx/2 + 1), 128x256 tiles
#define NCLS 100
#define PB 128              // prep streaming blocks
#define PROWS (BN / PB)     // 64
#define FBLKS 128           // finalize blocks (64 threads each)

// workspace layout (bytes)
#define OFF_FB    0                                 // 2 MB bf16 features
#define OFF_PART  (2 * 1024 * 1024)                 // 1 MB float [32][BN] row-side
#define OFF_CREC  (OFF_PART + 32 * BN * 4)          // 1.06 MB float [TILES][256]
#define OFF_G     (OFF_CREC + TILES * 256 * 4)      // 51.2 KB class sums
#define OFF_HIST  (OFF_G + NCLS * DK * 4)           // hist
#define OFF_BSUM  (OFF_HIST + 512)                  // block sums (FBLKS floats)
#define OFF_CTR   (OFF_BSUM + 1024)                 // arrival counter

typedef __attribute__((ext_vector_type(8))) short bf16x8;   // 8 bf16 = 4 VGPRs
typedef __attribute__((ext_vector_type(4))) float f32x4;

__device__ __forceinline__ unsigned short f2bf(float f) {
    unsigned u = __builtin_bit_cast(unsigned, f);
    u += 0x7fffu + ((u >> 16) & 1u);
    return (unsigned short)(u >> 16);
}

__device__ __forceinline__ float fexp2(float x) {
#if __has_builtin(__builtin_amdgcn_exp2f)
    return __builtin_amdgcn_exp2f(x);
#else
    float r; asm("v_exp_f32 %0, %1" : "=v"(r) : "v"(x)); return r;
#endif
}

__device__ __forceinline__ void load_lds16(const void* g, void* l) {
    __builtin_amdgcn_global_load_lds(
        (const __attribute__((address_space(1))) unsigned int*)g,
        (__attribute__((address_space(3))) unsigned int*)l, 16, 0, 0);
}

// prep: cast to bf16 + re-arm ctr. Pure streaming, nothing else.
__global__ __launch_bounds__(256) void prep_kernel(const float* __restrict__ F,
                                                   unsigned short* __restrict__ Fb,
                                                   unsigned int* __restrict__ ctr) {
    const int t = threadIdx.x;
    const int b = blockIdx.x;
    if (b == 0 && t == 0) *ctr = 0u;

    const float4* F4  = (const float4*)F + (size_t)b * (PROWS * DK / 4);
    ushort4*      Fb4 = (ushort4*)Fb + (size_t)b * (PROWS * DK / 4);
#pragma unroll
    for (int k = 0; k < PROWS * DK / 4 / 256; ++k) {   // 8
        float4 v = F4[k * 256 + t];
        ushort4 o;
        o.x = f2bf(v.x); o.y = f2bf(v.y); o.z = f2bf(v.z); o.w = f2bf(v.w);
        Fb4[k * 256 + t] = o;
    }
}

// rider block: class c — compact matching rows, sum F rows -> G[c], hist[c]
__device__ __forceinline__ void class_rider(const float* __restrict__ F,
                                            const int* __restrict__ labels,
                                            float* __restrict__ G,
                                            int* __restrict__ hist,
                                            int c, char* smem) {
    const int t    = threadIdx.x;
    int*      rows = (int*)smem;                   // 2048 ints = 8 KB
    int*      nrs  = (int*)(smem + 8192);
    float*    gh   = (float*)(smem + 8192 + 64);   // 256 floats

    if (t == 0) *nrs = 0;
    __syncthreads();
#pragma unroll
    for (int k = 0; k < BN / 256; ++k) {   // 32
        const int r = k * 256 + t;
        if (labels[r] == c) {
            const int idx = atomicAdd(nrs, 1);
            if (idx < 2048) rows[idx] = r;
        }
    }
    __syncthreads();
    const int n = *nrs;

    const int half = t >> 7, col = t & 127;
    float acc = 0.f;
    for (int j = half; j < n; j += 2)
        acc += F[(size_t)rows[j] * DK + col];
    gh[t] = acc;
    __syncthreads();
    if (t < DK) G[c * DK + t] = gh[t] + gh[t + DK];
    if (t == 0) hist[c] = n;
}

// one 128-row x 256-col tile at (bx, cy), cy <= bx>>1  (v7 staging/compute core)
template <bool DIAGT>
__device__ __forceinline__ void supcon_tile(const short* __restrict__ Fb,
                                            float* __restrict__ part,
                                            float* __restrict__ crec,
                                            int bx, int cy, int bid, char* smem) {
    const int t    = threadIdx.x;
    const int wave = t >> 6, lane = t & 63;
    const int quad = lane >> 4, l16 = lane & 15;
    const int rowBase = bx * 128 + wave * 32;
    const int colBase = cy * 256;
    float*    colred  = (float*)(smem + 32768);    // [4][256], beyond stage halves

    // slot-linear LDS B tiles (4 KB each): slot s=(kt*4+quad)*16+col holds
    // Fb[colBase+jt*16+col][kt*32+quad*8 ..+8]; per-lane pre-permuted GLOBAL
    // source, linear LDS dest (rule #21) -> conflict-free b128 reads.
    const char* Btile = (const char*)Fb + (size_t)colBase * 256;
    const int   gso   = (t & 15) * 256 + (t >> 6) * 64 + ((t >> 4) & 3) * 16;
    char*       ldsw  = smem + wave * 1024;

    // stage group 0 (tiles 0..3) into half 0
#pragma unroll
    for (int tt = 0; tt < 4; ++tt)
        load_lds16(Btile + tt * 4096 + gso, ldsw + tt * 4096);

    // A fragments: 32 rows x K=128 per wave
    bf16x8 a[2][4];
#pragma unroll
    for (int rt = 0; rt < 2; ++rt)
#pragma unroll
        for (int kt = 0; kt < 4; ++kt)
            a[rt][kt] = *(const bf16x8*)(Fb + (size_t)(rowBase + rt * 16 + l16) * DK
                                            + kt * 32 + quad * 8);

    float Zs[2][4];
#pragma unroll
    for (int rt = 0; rt < 2; ++rt)
#pragma unroll
        for (int r = 0; r < 4; ++r) Zs[rt][r] = 0.f;

    const int roffb = quad * 256 + l16 * 16;

    __syncthreads();   // group 0 staged

#pragma unroll
    for (int g = 0; g < 4; ++g) {
        if (g < 3) {   // stage next group into the other half
            char* dsth = smem + ((g + 1) & 1) * 16384 + wave * 1024;
#pragma unroll
            for (int tt = 0; tt < 4; ++tt)
                load_lds16(Btile + (size_t)((g + 1) * 4 + tt) * 4096 + gso,
                           dsth + tt * 4096);
        }
        const char* srch = smem + (g & 1) * 16384;
#pragma unroll
        for (int tt = 0; tt < 4; ++tt) {
            const int jt = g * 4 + tt;
            bf16x8 bb[4];
#pragma unroll
            for (int kt = 0; kt < 4; ++kt)
                bb[kt] = *(const bf16x8*)(srch + tt * 4096 + kt * 1024 + roffb);
            float Zc0 = 0.f, Zc1 = 0.f;
#pragma unroll
            for (int rt = 0; rt < 2; ++rt) {
                f32x4 acc = {0.f, 0.f, 0.f, 0.f};
#pragma unroll
                for (int kt = 0; kt < 4; ++kt)
                    acc = __builtin_amdgcn_mfma_f32_16x16x32_bf16(a[rt][kt], bb[kt],
                                                                  acc, 0, 0, 0);
#pragma unroll
                for (int r = 0; r < 4; ++r) {
                    float e = fexp2(fmaf(acc[r], C1F, -40.0f));
                    if (DIAGT) {
                        if (colBase + jt * 16 + l16 == rowBase + rt * 16 + quad * 4 + r)
                            e = 0.f;                       // Z excludes diagonal
                    }
                    Zs[rt][r] += e;                        // row-side
                    if (!DIAGT) { if (rt == 0) Zc0 += e; else Zc1 += e; }
                }
            }
            if (!DIAGT) {   // reduce over quads (wave's 32 rows) -> LDS, no atomics
                float Zc = Zc0 + Zc1;
                Zc += __shfl_xor(Zc, 16);
                Zc += __shfl_xor(Zc, 32);
                if (quad == 0) colred[wave * 256 + jt * 16 + l16] = Zc;
            }
        }
        if (g < 3) __syncthreads();   // next half staged; this half reusable
    }

    // row-side: slot cy single-writer across the grid -> plain store
#pragma unroll
    for (int rt = 0; rt < 2; ++rt)
#pragma unroll
        for (int r = 0; r < 4; ++r) {
            float zz = Zs[rt][r];
#pragma unroll
            for (int h = 1; h < 16; h <<= 1) zz += __shfl_xor(zz, h);
            if (l16 == 0)
                part[(size_t)cy * BN + rowBase + rt * 16 + quad * 4 + r] = zz;
        }

    // col-side: fold 4 waves' partials, single plain store per tile
    if (!DIAGT) {
        __syncthreads();
        crec[(size_t)bid * 256 + t] =
            colred[t] + colred[256 + t] + colred[512 + t] + colred[768 + t];
    }
}

__global__ __launch_bounds__(256, 2) void supcon_main(const short* __restrict__ Fb,
                                                      float* __restrict__ part,
                                                      float* __restrict__ crec,
                                                      const float* __restrict__ F,
                                                      const int* __restrict__ labels,
                                                      float* __restrict__ G,
                                                      int* __restrict__ hist) {
    __shared__ alignas(16) char smem[36864];   // 32 KB stage + 4 KB colred
    const int bid = blockIdx.x;
    if (bid >= TILES) {                        // 100 riders: per-class G/hist
        class_rider(F, labels, G, hist, bid - TILES, smem);
        return;
    }
    // decode: ranges [k^2, k^2+k) -> bx=2k-1; [k^2+k, (k+1)^2) -> bx=2k
    int k0 = (int)sqrtf((float)bid);
    while ((k0 + 1) * (k0 + 1) <= bid) ++k0;
    while (k0 * k0 > bid) --k0;
    int bx, cy;
    if (bid < k0 * k0 + k0) { bx = 2 * k0 - 1; cy = bid - k0 * k0; }
    else                    { bx = 2 * k0;     cy = bid - k0 * k0 - k0; }
    if (cy == (bx >> 1)) supcon_tile<true >(Fb, part, crec, bx, cy, bid, smem);
    else                 supcon_tile<false>(Fb, part, crec, bx, cy, bid, smem);
}

// 128 blocks x 64 threads: row-chunk c2 = bid>>2 block-uniform
__global__ __launch_bounds__(64) void supcon_finalize(const float* __restrict__ F,
                                                      const int* __restrict__ labels,
                                                      const float* __restrict__ part,
                                                      const float* __restrict__ crec,
                                                      const float* __restrict__ G,
                                                      const int* __restrict__ hist,
                                                      float* __restrict__ bsums,
                                                      unsigned int* __restrict__ ctr,
                                                      float* __restrict__ out) {
    const int t  = threadIdx.x;
    const int i  = blockIdx.x * 64 + t;
    const int c2 = blockIdx.x >> 2;   // i / 256
    const int cl = i & 255;

    // Z_i: row-side slots [0..c2] + col-records of tiles (bx, c2), bx>=2c2+2
    float Zm = 0.f;
    for (int k = 0; k <= c2; ++k) Zm += part[(size_t)k * BN + i];
    for (int k = c2 + 1; k < 32; ++k) {
        Zm += crec[(size_t)(k * k + k + c2) * 256 + cl];           // bx = 2k
        Zm += crec[(size_t)((k + 1) * (k + 1) + c2) * 256 + cl];   // bx = 2k+1
    }

    const int   lbl = labels[i];
    const float cnt = (float)(hist[lbl] - 1);

    const float4* fr = (const float4*)(F + (size_t)i * DK);
    const float4* gr = (const float4*)(G + lbl * DK);
    float dot = 0.f, nrm = 0.f;
#pragma unroll 8
    for (int k = 0; k < DK / 4; ++k) {
        const float4 av = fr[k], gv = gr[k];
        dot += av.x * gv.x + av.y * gv.y + av.z * gv.z + av.w * gv.w;
        nrm += av.x * av.x + av.y * av.y + av.z * av.z + av.w * av.w;
    }

    // m~ = s_ii/T; exact for any m~ (m only enters via the 1e-12 term)
    const float mt = nrm * INV_T;
    const float A  = (dot - nrm) * INV_T;
    float term = 0.f;
    if (cnt > 0.5f)
        term = (A - cnt * mt) / cnt - __logf(1e-12f + Zm * __expf(C40F - mt));

    float sum = term;
#pragma unroll
    for (int h = 1; h < 64; h <<= 1) sum += __shfl_xor(sum, h);

    __shared__ int lastf;
    if (t == 0) {
        bsums[blockIdx.x] = sum;
        __threadfence();
        const unsigned old = atomicAdd(ctr, 1u);
        lastf = (old == FBLKS - 1);
    }
    __syncthreads();
    if (lastf) {   // last block: wave-parallel fold of FBLKS partials
        const volatile float* vb = bsums;
        float v = vb[t] + vb[t + 64];
#pragma unroll
        for (int h = 1; h < 64; h <<= 1) v += __shfl_xor(v, h);
        if (t == 0) out[0] = -v * (1.0f / BN);
    }
}

extern "C" void kernel_launch(void* const* d_in, const int* in_sizes, int n_in,
                              void* d_out, int out_size, void* d_ws, size_t ws_size,
                              hipStream_t stream) {
    const float* F      = (const float*)d_in[0];
    const int*   labels = (const int*)d_in[1];
    // d_in[2] (fac_label) is a no-op in the reference math.
    float* out = (float*)d_out;
    char*  ws  = (char*)d_ws;

    unsigned short* Fb    = (unsigned short*)(ws + OFF_FB);
    float*          part  = (float*)(ws + OFF_PART);
    float*          crec  = (float*)(ws + OFF_CREC);
    float*          G     = (float*)(ws + OFF_G);
    int*            hist  = (int*)(ws + OFF_HIST);
    float*          bsums = (float*)(ws + OFF_BSUM);
    unsigned int*   ctr   = (unsigned int*)(ws + OFF_CTR);

    prep_kernel<<<PB, 256, 0, stream>>>(F, Fb, ctr);
    supcon_main<<<TILES + NCLS, 256, 0, stream>>>((const short*)Fb, part, crec,
                                                  F, labels, G, hist);
    supcon_finalize<<<FBLKS, 64, 0, stream>>>(F, labels, part, crec, G, hist,
                                              bsums, ctr, out);
}